// Round 9
// baseline (104.274 us; speedup 1.0000x reference)
//
#include <hip/hip_runtime.h>

#define BN 64
#define TN 1024
#define VN 1024
#define UNITSN 512
#define TWO_PI 6.283185307179586476925286766559f

// K1: s[b*1024+tau] = sum_v x[b, tau, v].
// Fill-kernel-style schedule: 2048 blocks (8/CU) grid-stride, each wave
// processes 8 rows (one row per iteration, same per-instruction pattern as
// R5's measured-best: 64 lanes x consecutive float4).  Independent shuffle
// chains from consecutive iterations overlap; per-wave stream is 8x longer.
__global__ void k_reduce_v(const float* __restrict__ x, float* __restrict__ s) {
    int waveId = blockIdx.x * 4 + (threadIdx.x >> 6);   // 0..8191
    int lane   = threadIdx.x & 63;
#pragma unroll
    for (int it = 0; it < 8; ++it) {
        int row = it * 8192 + waveId;
        const float4* xr = reinterpret_cast<const float4*>(x) + (size_t)row * (VN / 4);
        float acc = 0.f;
#pragma unroll
        for (int i = 0; i < 4; ++i) {
            float4 v = xr[i * 64 + lane];
            acc += (v.x + v.y) + (v.z + v.w);
        }
#pragma unroll
        for (int off = 32; off > 0; off >>= 1)
            acc += __shfl_down(acc, off, 64);
        if (lane == 0) s[row] = acc;
    }
}

// K2: F[b*512+t] = sum_tau s[b,tau] * e^{-2*pi*i*tau*t/1024}, t in [0,512)
// One WAVE per (b,t); twiddle from integer phase via hw v_sin/v_cos (full ILP).
// (R5 exact — measured-best middle.)
__global__ void k_dft(const float* __restrict__ s, float2* __restrict__ F) {
    int w    = (blockIdx.x * blockDim.x + threadIdx.x) >> 6;  // global wave id
    int lane = threadIdx.x & 63;
    int b    = w >> 9;
    int t    = w & 511;
    const float* sb = s + b * TN;

    int p  = (lane * t) & 1023;        // phase index tau*t mod 1024
    int st = (64 * t) & 1023;          // per-step phase increment

    float ar = 0.f, ai = 0.f;
#pragma unroll
    for (int i = 0; i < 16; ++i) {
        float sv  = sb[lane + 64 * i];
        float ang = (float)p * (-TWO_PI / 1024.0f);
        float c   = __cosf(ang);
        float n   = __sinf(ang);
        ar = fmaf(sv, c, ar);
        ai = fmaf(sv, n, ai);
        p  = (p + st) & 1023;
    }
#pragma unroll
    for (int off = 32; off > 0; off >>= 1) {
        ar += __shfl_xor(ar, off, 64);
        ai += __shfl_xor(ai, off, 64);
    }
    if (lane == 0) F[b * UNITSN + t] = make_float2(ar, ai);
}

// K3: W[b,t] = (1/2048) * sum_k (Br[b,k] + i*Bi[b,k]) * F[k,t]
// Wave = 16 t-values x 4 k-segments; shuffle-combine.  (R5 exact.)
__global__ void k_matmul(const float* __restrict__ Br, const float* __restrict__ Bi,
                         const float2* __restrict__ F, float2* __restrict__ W) {
    int tid   = threadIdx.x;
    int lane  = tid & 63;
    int wv    = tid >> 6;
    int b     = blockIdx.x >> 3;
    int tbase = ((blockIdx.x & 7) * 4 + wv) * 16;
    int t     = tbase + (lane & 15);
    int seg   = lane >> 4;
    const float* brp = Br + b * 64 + seg * 16;
    const float* bip = Bi + b * 64 + seg * 16;
    float wr = 0.f, wi = 0.f;
#pragma unroll
    for (int i = 0; i < 16; ++i) {
        float br = brp[i];
        float bi = bip[i];
        float2 f = F[(seg * 16 + i) * UNITSN + t];
        wr = fmaf(br, f.x, wr); wr = fmaf(-bi, f.y, wr);
        wi = fmaf(br, f.y, wi); wi = fmaf(bi, f.x, wi);
    }
    wr += __shfl_xor(wr, 16, 64); wi += __shfl_xor(wi, 16, 64);
    wr += __shfl_xor(wr, 32, 64); wi += __shfl_xor(wi, 32, 64);
    if (seg == 0) {
        const float coef = 1.0f / 2048.0f;
        W[b * UNITSN + t] = make_float2(wr * coef, wi * coef);
    }
}

// K4: out[b][j][t][{re,im}] = W[b,t] + (t+j-511 >= 0 ? W[b, t+j-511] : 0)
// Fill-kernel-style schedule: 2048 blocks grid-stride, 16 float4 stores per
// thread.  Per-instruction pattern identical to R5's measured-best (lanes
// write consecutive float4s); idx -> (b,j,t2) map unchanged.
__global__ void k_expand(const float2* __restrict__ W, float4* __restrict__ out) {
    int base = blockIdx.x * 256 + threadIdx.x;
#pragma unroll 4
    for (int it = 0; it < 16; ++it) {
        int idx = it * (2048 * 256) + base;           // 64*512*256 total
        int t2 = (idx & 255) * 2;
        int j  = (idx >> 8) & 511;
        int b  = idx >> 17;
        const float2* Wb = W + b * UNITSN;
        float4 w01 = *reinterpret_cast<const float4*>(Wb + t2);  // W[t2], W[t2+1]
        int k0 = t2 + j - 511;
        float2 z0 = (k0 >= 0)     ? Wb[k0]     : make_float2(0.f, 0.f);
        float2 z1 = (k0 + 1 >= 0) ? Wb[k0 + 1] : make_float2(0.f, 0.f);
        out[idx] = make_float4(w01.x + z0.x, w01.y + z0.y, w01.z + z1.x, w01.w + z1.y);
    }
}

extern "C" void kernel_launch(void* const* d_in, const int* in_sizes, int n_in,
                              void* d_out, int out_size, void* d_ws, size_t ws_size,
                              hipStream_t stream) {
    const float* x  = (const float*)d_in[0];
    // d_in[1], d_in[2] (A_r, A_i) are provably unused: the shift-register state's
    // column 0 stays zero for all 512 scan steps.
    const float* Br = (const float*)d_in[3];
    const float* Bi = (const float*)d_in[4];

    char* ws = (char*)d_ws;
    float*  s = (float*)ws;                       // 64*1024 f32 = 256 KB
    float2* F = (float2*)(ws + 256 * 1024);       // 64*512 cplx = 256 KB
    float2* W = (float2*)(ws + 512 * 1024);       // 64*512 cplx = 256 KB

    // K1: 2048 blocks grid-stride, 8 rows per wave
    k_reduce_v<<<2048, 256, 0, stream>>>(x, s);
    // K2: 64 b * 512 t waves, 4 waves/block
    k_dft<<<(BN * UNITSN) / 4, 256, 0, stream>>>(s, F);
    // K3: 64 b * 8 t-chunks (wave = 16t x 4seg)
    k_matmul<<<BN * 8, 256, 0, stream>>>(Br, Bi, F, W);
    // K4: 2048 blocks grid-stride, 16 float4 per thread
    k_expand<<<2048, 256, 0, stream>>>(W, (float4*)d_out);
}

// Round 10
// 99.116 us; speedup vs baseline: 1.0520x; 1.0520x over previous
//
#include <hip/hip_runtime.h>

#define BN 64
#define TN 1024
#define VN 1024
#define UNITSN 512
#define TWO_PI 6.283185307179586476925286766559f

// K1: s[b*1024+tau] = sum_v x[b, tau, v].  One wave (64 lanes) per row of 1024 floats.
// Measured-best K1 shape (R5; beats 2-row R8, grid-stride R9, NT R6).
__global__ void k_reduce_v(const float* __restrict__ x, float* __restrict__ s) {
    int row  = blockIdx.x * 4 + (threadIdx.x >> 6);   // 4 waves per 256-thread block
    int lane = threadIdx.x & 63;
    const float4* xr = reinterpret_cast<const float4*>(x) + (size_t)row * (VN / 4);
    float acc = 0.f;
#pragma unroll
    for (int i = 0; i < 4; ++i) {
        float4 v = xr[i * 64 + lane];                 // consecutive lanes -> consecutive 16B
        acc += (v.x + v.y) + (v.z + v.w);
    }
#pragma unroll
    for (int off = 32; off > 0; off >>= 1)
        acc += __shfl_down(acc, off, 64);
    if (lane == 0) s[row] = acc;
}

// K2: F[b*512+t] = sum_tau s[b,tau] * e^{-2*pi*i*tau*t/1024}, t in [0,512)
// One WAVE per (b,t); twiddle from integer phase via hw v_sin/v_cos (full ILP,
// no serial rotation chain, no libm).  Measured-best middle (R5).
__global__ void k_dft(const float* __restrict__ s, float2* __restrict__ F) {
    int w    = (blockIdx.x * blockDim.x + threadIdx.x) >> 6;  // global wave id
    int lane = threadIdx.x & 63;
    int b    = w >> 9;
    int t    = w & 511;
    const float* sb = s + b * TN;

    int p  = (lane * t) & 1023;        // phase index tau*t mod 1024
    int st = (64 * t) & 1023;          // per-step phase increment

    float ar = 0.f, ai = 0.f;
#pragma unroll
    for (int i = 0; i < 16; ++i) {
        float sv  = sb[lane + 64 * i];
        float ang = (float)p * (-TWO_PI / 1024.0f);
        float c   = __cosf(ang);
        float n   = __sinf(ang);
        ar = fmaf(sv, c, ar);
        ai = fmaf(sv, n, ai);
        p  = (p + st) & 1023;
    }
#pragma unroll
    for (int off = 32; off > 0; off >>= 1) {
        ar += __shfl_xor(ar, off, 64);
        ai += __shfl_xor(ai, off, 64);
    }
    if (lane == 0) F[b * UNITSN + t] = make_float2(ar, ai);
}

// K3: W[b,t] = (1/2048) * sum_k (Br[b,k] + i*Bi[b,k]) * F[k,t]
// Wave = 16 t-values x 4 k-segments; shuffle-combine.  (R5 exact.)
__global__ void k_matmul(const float* __restrict__ Br, const float* __restrict__ Bi,
                         const float2* __restrict__ F, float2* __restrict__ W) {
    int tid   = threadIdx.x;
    int lane  = tid & 63;
    int wv    = tid >> 6;
    int b     = blockIdx.x >> 3;
    int tbase = ((blockIdx.x & 7) * 4 + wv) * 16;
    int t     = tbase + (lane & 15);
    int seg   = lane >> 4;
    const float* brp = Br + b * 64 + seg * 16;
    const float* bip = Bi + b * 64 + seg * 16;
    float wr = 0.f, wi = 0.f;
#pragma unroll
    for (int i = 0; i < 16; ++i) {
        float br = brp[i];
        float bi = bip[i];
        float2 f = F[(seg * 16 + i) * UNITSN + t];
        wr = fmaf(br, f.x, wr); wr = fmaf(-bi, f.y, wr);
        wi = fmaf(br, f.y, wi); wi = fmaf(bi, f.x, wi);
    }
    wr += __shfl_xor(wr, 16, 64); wi += __shfl_xor(wi, 16, 64);
    wr += __shfl_xor(wr, 32, 64); wi += __shfl_xor(wi, 32, 64);
    if (seg == 0) {
        const float coef = 1.0f / 2048.0f;
        W[b * UNITSN + t] = make_float2(wr * coef, wi * coef);
    }
}

// K4: out[b][j][t][{re,im}] = W[b,t] + (t+j-511 >= 0 ? W[b, t+j-511] : 0)
// One thread writes 2 consecutive t's as one float4: lanes write consecutive
// 16B -> perfect per-instruction coalescing.  Measured-best K4 shape (R2/R5).
__global__ void k_expand(const float2* __restrict__ W, float4* __restrict__ out) {
    int idx = blockIdx.x * 256 + threadIdx.x;         // 64*512*256 total
    int t2 = (idx & 255) * 2;
    int j  = (idx >> 8) & 511;
    int b  = idx >> 17;
    const float2* Wb = W + b * UNITSN;
    float4 w01 = *reinterpret_cast<const float4*>(Wb + t2);  // W[t2], W[t2+1]
    int k0 = t2 + j - 511;
    float2 z0 = (k0 >= 0)     ? Wb[k0]     : make_float2(0.f, 0.f);
    float2 z1 = (k0 + 1 >= 0) ? Wb[k0 + 1] : make_float2(0.f, 0.f);
    out[idx] = make_float4(w01.x + z0.x, w01.y + z0.y, w01.z + z1.x, w01.w + z1.y);
}

extern "C" void kernel_launch(void* const* d_in, const int* in_sizes, int n_in,
                              void* d_out, int out_size, void* d_ws, size_t ws_size,
                              hipStream_t stream) {
    const float* x  = (const float*)d_in[0];
    // d_in[1], d_in[2] (A_r, A_i) are provably unused: the shift-register state's
    // column 0 stays zero for all 512 scan steps.
    const float* Br = (const float*)d_in[3];
    const float* Bi = (const float*)d_in[4];

    char* ws = (char*)d_ws;
    float*  s = (float*)ws;                       // 64*1024 f32 = 256 KB
    float2* F = (float2*)(ws + 256 * 1024);       // 64*512 cplx = 256 KB
    float2* W = (float2*)(ws + 512 * 1024);       // 64*512 cplx = 256 KB

    // K1: 65536 rows, 4 rows/block
    k_reduce_v<<<BN * TN / 4, 256, 0, stream>>>(x, s);
    // K2: 64 b * 512 t waves, 4 waves/block
    k_dft<<<(BN * UNITSN) / 4, 256, 0, stream>>>(s, F);
    // K3: 64 b * 8 t-chunks (wave = 16t x 4seg)
    k_matmul<<<BN * 8, 256, 0, stream>>>(Br, Bi, F, W);
    // K4: 64*512*256 threads
    k_expand<<<(BN * UNITSN * (UNITSN / 2)) / 256, 256, 0, stream>>>(W, (float4*)d_out);
}

// Round 11
// 79.588 us; speedup vs baseline: 1.3102x; 1.2454x over previous
//
#include <hip/hip_runtime.h>

#define BN 64
#define TN 1024
#define VN 1024
#define UNITSN 512
#define TWO_PI 6.283185307179586476925286766559f

typedef __attribute__((ext_vector_type(4))) float f32x4;

// K1: s[b*1024+tau] = sum_v x[b, tau, v].  One wave (64 lanes) per row of 1024
// floats — R5's measured-best shape, byte-identical access pattern; ONLY change
// vs R5: nontemporal loads (x is a 256MB write-never stream; skip L2 alloc).
__global__ void k_reduce_v(const float* __restrict__ x, float* __restrict__ s) {
    int row  = blockIdx.x * 4 + (threadIdx.x >> 6);   // 4 waves per 256-thread block
    int lane = threadIdx.x & 63;
    const f32x4* xr = reinterpret_cast<const f32x4*>(x) + (size_t)row * (VN / 4);
    float acc = 0.f;
#pragma unroll
    for (int i = 0; i < 4; ++i) {
        f32x4 v = __builtin_nontemporal_load(&xr[i * 64 + lane]);
        acc += (v.x + v.y) + (v.z + v.w);
    }
#pragma unroll
    for (int off = 32; off > 0; off >>= 1)
        acc += __shfl_down(acc, off, 64);
    if (lane == 0) s[row] = acc;
}

// K2: F[b*512+t] = sum_tau s[b,tau] * e^{-2*pi*i*tau*t/1024}, t in [0,512)
// One WAVE per (b,t); twiddle from integer phase via hw v_sin/v_cos.  (R5 exact.)
__global__ void k_dft(const float* __restrict__ s, float2* __restrict__ F) {
    int w    = (blockIdx.x * blockDim.x + threadIdx.x) >> 6;  // global wave id
    int lane = threadIdx.x & 63;
    int b    = w >> 9;
    int t    = w & 511;
    const float* sb = s + b * TN;

    int p  = (lane * t) & 1023;        // phase index tau*t mod 1024
    int st = (64 * t) & 1023;          // per-step phase increment

    float ar = 0.f, ai = 0.f;
#pragma unroll
    for (int i = 0; i < 16; ++i) {
        float sv  = sb[lane + 64 * i];
        float ang = (float)p * (-TWO_PI / 1024.0f);
        float c   = __cosf(ang);
        float n   = __sinf(ang);
        ar = fmaf(sv, c, ar);
        ai = fmaf(sv, n, ai);
        p  = (p + st) & 1023;
    }
#pragma unroll
    for (int off = 32; off > 0; off >>= 1) {
        ar += __shfl_xor(ar, off, 64);
        ai += __shfl_xor(ai, off, 64);
    }
    if (lane == 0) F[b * UNITSN + t] = make_float2(ar, ai);
}

// K3: W[b,t] = (1/2048) * sum_k (Br[b,k] + i*Bi[b,k]) * F[k,t]
// Wave = 16 t-values x 4 k-segments; shuffle-combine.  (R5 exact.)
__global__ void k_matmul(const float* __restrict__ Br, const float* __restrict__ Bi,
                         const float2* __restrict__ F, float2* __restrict__ W) {
    int tid   = threadIdx.x;
    int lane  = tid & 63;
    int wv    = tid >> 6;
    int b     = blockIdx.x >> 3;
    int tbase = ((blockIdx.x & 7) * 4 + wv) * 16;
    int t     = tbase + (lane & 15);
    int seg   = lane >> 4;
    const float* brp = Br + b * 64 + seg * 16;
    const float* bip = Bi + b * 64 + seg * 16;
    float wr = 0.f, wi = 0.f;
#pragma unroll
    for (int i = 0; i < 16; ++i) {
        float br = brp[i];
        float bi = bip[i];
        float2 f = F[(seg * 16 + i) * UNITSN + t];
        wr = fmaf(br, f.x, wr); wr = fmaf(-bi, f.y, wr);
        wi = fmaf(br, f.y, wi); wi = fmaf(bi, f.x, wi);
    }
    wr += __shfl_xor(wr, 16, 64); wi += __shfl_xor(wi, 16, 64);
    wr += __shfl_xor(wr, 32, 64); wi += __shfl_xor(wi, 32, 64);
    if (seg == 0) {
        const float coef = 1.0f / 2048.0f;
        W[b * UNITSN + t] = make_float2(wr * coef, wi * coef);
    }
}

// K4: out[b][j][t][{re,im}] = W[b,t] + (t+j-511 >= 0 ? W[b, t+j-511] : 0)
// R5's measured-best shape (thread writes 2 consecutive t's as one float4,
// lanes -> consecutive 16B); ONLY change vs R5: nontemporal stores (output is
// a 134MB write-once stream; skip L2 alloc / eviction churn).
__global__ void k_expand(const float2* __restrict__ W, f32x4* __restrict__ out) {
    int idx = blockIdx.x * 256 + threadIdx.x;         // 64*512*256 total
    int t2 = (idx & 255) * 2;
    int j  = (idx >> 8) & 511;
    int b  = idx >> 17;
    const float2* Wb = W + b * UNITSN;
    const f32x4 w01 = *reinterpret_cast<const f32x4*>(Wb + t2);  // W[t2], W[t2+1]
    int k0 = t2 + j - 511;
    float2 z0 = (k0 >= 0)     ? Wb[k0]     : make_float2(0.f, 0.f);
    float2 z1 = (k0 + 1 >= 0) ? Wb[k0 + 1] : make_float2(0.f, 0.f);
    f32x4 o = {w01.x + z0.x, w01.y + z0.y, w01.z + z1.x, w01.w + z1.y};
    __builtin_nontemporal_store(o, &out[idx]);
}

extern "C" void kernel_launch(void* const* d_in, const int* in_sizes, int n_in,
                              void* d_out, int out_size, void* d_ws, size_t ws_size,
                              hipStream_t stream) {
    const float* x  = (const float*)d_in[0];
    // d_in[1], d_in[2] (A_r, A_i) are provably unused: the shift-register state's
    // column 0 stays zero for all 512 scan steps.
    const float* Br = (const float*)d_in[3];
    const float* Bi = (const float*)d_in[4];

    char* ws = (char*)d_ws;
    float*  s = (float*)ws;                       // 64*1024 f32 = 256 KB
    float2* F = (float2*)(ws + 256 * 1024);       // 64*512 cplx = 256 KB
    float2* W = (float2*)(ws + 512 * 1024);       // 64*512 cplx = 256 KB

    // K1: 65536 rows, 4 rows/block
    k_reduce_v<<<BN * TN / 4, 256, 0, stream>>>(x, s);
    // K2: 64 b * 512 t waves, 4 waves/block
    k_dft<<<(BN * UNITSN) / 4, 256, 0, stream>>>(s, F);
    // K3: 64 b * 8 t-chunks (wave = 16t x 4seg)
    k_matmul<<<BN * 8, 256, 0, stream>>>(Br, Bi, F, W);
    // K4: 64*512*256 threads
    k_expand<<<(BN * UNITSN * (UNITSN / 2)) / 256, 256, 0, stream>>>(W, (f32x4*)d_out);
}